// Round 1
// baseline (494.080 us; speedup 1.0000x reference)
//
#include <hip/hip_runtime.h>
#include <stdint.h>

typedef short short8 __attribute__((ext_vector_type(8)));
typedef float f32x4 __attribute__((ext_vector_type(4)));

#define D 128
// H == 128 as well

__device__ __forceinline__ unsigned short f2bf(float f) {
    union { float f; unsigned u; } v; v.f = f;
    unsigned u = v.u;
    unsigned r = (u + 0x7FFFu + ((u >> 16) & 1u)) >> 16;  // RNE
    return (unsigned short)r;
}

// ---------------------------------------------------------------------------
// Kernel 1: pre-pack Wu (f32 [H][D]) into bf16 MFMA B-fragments.
// Fragment index t = nt*256 + kk*64 + lane holds B[k][col] for
// col = nt*16 + (lane&15), k = kk*32 + (lane>>4)*8 + j, j=0..7,
// where B[k][col] = Wu[col][k]  (u = f @ Wu^T).
// ---------------------------------------------------------------------------
__global__ __launch_bounds__(256) void pack_wu(const float* __restrict__ Wu,
                                               short8* __restrict__ frag) {
    int tid = blockIdx.x * 256 + threadIdx.x;      // 0..2047
    int nt = tid >> 8, kk = (tid >> 6) & 3, l = tid & 63;
    int col = nt * 16 + (l & 15);
    int kb  = kk * 32 + ((l >> 4) * 8);
    short8 o;
#pragma unroll
    for (int j = 0; j < 8; ++j) o[j] = (short)f2bf(Wu[col * D + kb + j]);
    frag[tid] = o;
}

// ---------------------------------------------------------------------------
// Kernel 2: per-graph gate vectors  vIb[g][h] = Wv[h,:]·xI[last_g,:] + bu[h]
//                                   vVb[g][h] = Wv[h,:]·xV[last_g,:] + bu[h]
// ---------------------------------------------------------------------------
__global__ __launch_bounds__(128) void gate_k(const float* __restrict__ xI,
                                              const float* __restrict__ xV,
                                              const float* __restrict__ Wv,
                                              const float* __restrict__ bu,
                                              const int* __restrict__ lastn,
                                              float* __restrict__ vIb,
                                              float* __restrict__ vVb) {
    __shared__ float xi[D], xv[D];
    int g = blockIdx.x, t = threadIdx.x;
    int r = lastn[g];
    xi[t] = xI[(size_t)r * D + t];
    xv[t] = xV[(size_t)r * D + t];
    __syncthreads();
    const float4* wr = (const float4*)(Wv + (size_t)t * D);
    const float4* a4 = (const float4*)xi;
    const float4* b4 = (const float4*)xv;
    float sI = 0.f, sV = 0.f;
#pragma unroll 8
    for (int i = 0; i < D / 4; ++i) {
        float4 w = wr[i], a = a4[i], b = b4[i];
        sI += w.x * a.x + w.y * a.y + w.z * a.z + w.w * a.w;
        sV += w.x * b.x + w.y * b.y + w.z * b.z + w.w * b.w;
    }
    float bias = bu[t];
    vIb[(size_t)g * D + t] = sI + bias;
    vVb[(size_t)g * D + t] = sV + bias;
}

// ---------------------------------------------------------------------------
// Kernel 3: fused main. One block per graph, 4 waves, online softmax.
// ---------------------------------------------------------------------------
__global__ __launch_bounds__(256) void attn_main(
    const float* __restrict__ xI, const float* __restrict__ xV,
    const float* __restrict__ We, const int* __restrict__ lastn,
    const float* __restrict__ vIb, const float* __restrict__ vVb,
    const short8* __restrict__ fragG, float* __restrict__ out, int B) {
    __shared__ short8 bfrag[2048];       // 32 KB: Wu bf16 fragments
    __shared__ float cmbA[2][4][128];    // per-wave weighted sums
    __shared__ float cmbM[2][4];
    __shared__ float cmbL[2][4];

    int g = blockIdx.x;
    int t = threadIdx.x, lane = t & 63, w = t >> 6;

    // stage Wu fragments into LDS (contiguous 16B/lane -> conflict-free b128)
    {
        const uint4* src = (const uint4*)fragG;
        uint4* dst = (uint4*)bfrag;
#pragma unroll
        for (int i = 0; i < 8; ++i) dst[i * 256 + t] = src[i * 256 + t];
    }

    int s = (g == 0) ? 0 : (lastn[g - 1] + 1);
    int n = lastn[g] + 1 - s;                       // >= 1

    // per-lane epilogue constants: col = nt*16 + (lane&15)
    float WeR[8], vIR[8], vVR[8];
#pragma unroll
    for (int nt = 0; nt < 8; ++nt) {
        int col = nt * 16 + (lane & 15);
        WeR[nt] = We[col];
        vIR[nt] = vIb[(size_t)g * D + col];
        vVR[nt] = vVb[(size_t)g * D + col];
    }
    __syncthreads();

    float mI = -__builtin_inff(), mV = -__builtin_inff();
    float lIs = 0.f, lVs = 0.f;
    float aI0 = 0.f, aI1 = 0.f, aV0 = 0.f, aV1 = 0.f;

    int ch = (n + 15) >> 4;      // chunks per half
    int total = 2 * ch;

    for (int c = w; c < total; c += 4) {
        int half = (c >= ch) ? 1 : 0;
        const float* src = half ? xV : xI;
        int base = (c - half * ch) * 16;

        // ---- A fragments: row = lane&15, k = kk*32 + (lane>>4)*8 + j ----
        int arow = base + (lane & 15);
        if (arow > n - 1) arow = n - 1;             // clamp (masked later)
        const float* rp = src + (size_t)(s + arow) * D + ((lane >> 4) * 8);
        short8 af[4];
#pragma unroll
        for (int kk = 0; kk < 4; ++kk) {
            float4 f0 = *(const float4*)(rp + kk * 32);
            float4 f1 = *(const float4*)(rp + kk * 32 + 4);
            short8 a;
            a[0] = (short)f2bf(f0.x); a[1] = (short)f2bf(f0.y);
            a[2] = (short)f2bf(f0.z); a[3] = (short)f2bf(f0.w);
            a[4] = (short)f2bf(f1.x); a[5] = (short)f2bf(f1.y);
            a[6] = (short)f2bf(f1.z); a[7] = (short)f2bf(f1.w);
            af[kk] = a;
        }

        // ---- GEMM + gate epilogue; pI[q] = partial e for row (lane>>4)*4+q
        float pI[4] = {0.f, 0.f, 0.f, 0.f}, pV[4] = {0.f, 0.f, 0.f, 0.f};
#pragma unroll
        for (int nt = 0; nt < 8; ++nt) {
            f32x4 dacc = {0.f, 0.f, 0.f, 0.f};
#pragma unroll
            for (int kk = 0; kk < 4; ++kk)
                dacc = __builtin_amdgcn_mfma_f32_16x16x32_bf16(
                    af[kk], bfrag[nt * 256 + kk * 64 + lane], dacc, 0, 0, 0);
#pragma unroll
            for (int q = 0; q < 4; ++q) {
                float u  = dacc[q];
                float zI = u + vIR[nt];
                float zV = u + vVR[nt];
                pI[q] += WeR[nt] * __builtin_amdgcn_rcpf(1.f + __expf(-zI));
                pV[q] += WeR[nt] * __builtin_amdgcn_rcpf(1.f + __expf(-zV));
            }
        }
        // reduce across the 16 lanes of each quarter (cols), mask invalid rows
#pragma unroll
        for (int q = 0; q < 4; ++q) {
#pragma unroll
            for (int off = 1; off < 16; off <<= 1) {
                pI[q] += __shfl_xor(pI[q], off);
                pV[q] += __shfl_xor(pV[q], off);
            }
            int r = ((lane >> 4) * 4) + q;
            if (base + r >= n) { pI[q] = -__builtin_inff(); pV[q] = -__builtin_inff(); }
        }
        // chunk max over all 16 rows
        float cmI = fmaxf(fmaxf(pI[0], pI[1]), fmaxf(pI[2], pI[3]));
        float cmV = fmaxf(fmaxf(pV[0], pV[1]), fmaxf(pV[2], pV[3]));
        cmI = fmaxf(cmI, __shfl_xor(cmI, 16)); cmI = fmaxf(cmI, __shfl_xor(cmI, 32));
        cmV = fmaxf(cmV, __shfl_xor(cmV, 16)); cmV = fmaxf(cmV, __shfl_xor(cmV, 32));

        float mnI = fmaxf(mI, cmI), mnV = fmaxf(mV, cmV);
        float scI = __expf(mI - mnI), scV = __expf(mV - mnV);
        lIs *= scI; lVs *= scV;
        aI0 *= scI; aI1 *= scI; aV0 *= scV; aV1 *= scV;

        // online accumulate: rows re-read from L1 (just loaded as fragments)
#pragma unroll
        for (int r = 0; r < 16; ++r) {
            float eIr = __shfl(pI[r & 3], (r >> 2) << 4);
            float eVr = __shfl(pV[r & 3], (r >> 2) << 4);
            float wI = __expf(eIr - mnI);     // 0 for invalid rows (e = -inf)
            float wV = __expf(eVr - mnV);
            int rr = base + r; if (rr > n - 1) rr = n - 1;
            const float* fp = src + (size_t)(s + rr) * D;
            float f0 = fp[lane], f1 = fp[64 + lane];
            lIs += wI; lVs += wV;
            aI0 += wI * f0; aI1 += wI * f1;
            aV0 += wV * f0; aV1 += wV * f1;
        }
        mI = mnI; mV = mnV;
    }

    // ---- cross-wave flash combine ----
    cmbA[0][w][lane] = aI0; cmbA[0][w][lane + 64] = aI1;
    cmbA[1][w][lane] = aV0; cmbA[1][w][lane + 64] = aV1;
    if (lane == 0) {
        cmbM[0][w] = mI; cmbL[0][w] = lIs;
        cmbM[1][w] = mV; cmbL[1][w] = lVs;
    }
    __syncthreads();
    {
        int st = t >> 7, d = t & 127;     // 256 threads = 2 streams x 128 dims
        float M = fmaxf(fmaxf(cmbM[st][0], cmbM[st][1]),
                        fmaxf(cmbM[st][2], cmbM[st][3]));
        float Ls = 0.f, A = 0.f;
#pragma unroll
        for (int ww = 0; ww < 4; ++ww) {
            float e = __expf(cmbM[st][ww] - M);   // 0 for idle waves (m=-inf)
            Ls += cmbL[st][ww] * e;
            A  += cmbA[st][ww][d] * e;
        }
        out[(size_t)st * B * D + (size_t)g * D + d] = A * __builtin_amdgcn_rcpf(Ls);
    }
}

// ---------------------------------------------------------------------------
extern "C" void kernel_launch(void* const* d_in, const int* in_sizes, int n_in,
                              void* d_out, int out_size, void* d_ws, size_t ws_size,
                              hipStream_t stream) {
    const float* xI    = (const float*)d_in[0];
    const float* xV    = (const float*)d_in[1];
    const float* Wu    = (const float*)d_in[2];
    const float* bu    = (const float*)d_in[3];
    const float* Wv    = (const float*)d_in[4];
    const float* We    = (const float*)d_in[5];
    // d_in[6] = seg_ids (unused: segments are contiguous, last_nodes suffices)
    const int*   lastn = (const int*)d_in[7];
    const int B = in_sizes[7];               // 8192

    // workspace layout: vIb [B*D] f32 | vVb [B*D] f32 | Wu bf16 fragments 32KB
    float*  vIb   = (float*)d_ws;
    float*  vVb   = vIb + (size_t)B * D;
    short8* fragW = (short8*)(vVb + (size_t)B * D);

    pack_wu<<<8, 256, 0, stream>>>(Wu, fragW);
    gate_k<<<B, 128, 0, stream>>>(xI, xV, Wv, bu, lastn, vIb, vVb);
    attn_main<<<B, 256, 0, stream>>>(xI, xV, We, lastn, vIb, vVb, fragW,
                                     (float*)d_out, B);
}